// Round 22
// baseline (5820.771 us; speedup 1.0000x reference)
//
#include <hip/hip_runtime.h>

#define BB 32
#define NN 16384
#define CC 64
#define NC 4096
#define T  1024            // 16 waves/block = 4 waves/SIMD, 1 block/CU
#define SLOTS (NN / T)     // 16 points per thread -> 64-float state
#define NW (T / 64)        // 16 waves

// ---------------------------------------------------------------------------
// FPS, one block per batch. Distance chain B1 = fma(dz,dz, fma(dx,dx, dy*dy))
// — bitwise-verified vs reference (R6, absmax 0).
// R22: T=1024 + amdgpu_waves_per_eu(4,4).
//   R11-R21 established the loop is VALU-issue-bound (97% active-CU busy)
//   with ~300 accvgpr-move insts/iter taxing the 128-float state (arch cap
//   ~88 at T=512). At T=1024 the state is only 64 floats; waves_per_eu(4,4)
//   pins 1 block/CU -> 128-reg budget -> state + temps fit in arch VGPRs,
//   eliminating the tax. Total VALU issue is T-invariant, so the loop should
//   drop to its arithmetic floor. (R7's T=1024 had min-only launch_bounds:
//   heuristic targeted 2 blocks/CU -> 64-reg cap -> 48 VGPRs + tax.)
// Kept (proven): fused u64 single-barrier argmax [R21]: per wave value
// DPP-chain -> readlane; achievers rescan descending (first slot); complement
// index DPP-chain; lane63 u64 LDS atomicMax {dist bits, 0x7FFFFFFF-idx}
// (ties -> smallest index = numpy argmax). Depth-4 sentinel rotation.
// Compact 12B-row xyz buffer in d_ws for init + centroid reload [R12/R21].
// ---------------------------------------------------------------------------

template <int CTRL>
__device__ __forceinline__ float dpp_max_f(float x) {
    const int yi = __builtin_amdgcn_update_dpp(0, __float_as_int(x),
                                               CTRL, 0xf, 0xf, true);
    return fmaxf(x, __int_as_float(yi));
}
template <int CTRL>
__device__ __forceinline__ int dpp_max_i(int x) {
    const int y = __builtin_amdgcn_update_dpp(0, x, CTRL, 0xf, 0xf, true);
    return (x > y) ? x : y;
}

__device__ __forceinline__ float wave_max_f(float x) {
    x = dpp_max_f<0x111>(x);   // row_shr:1
    x = dpp_max_f<0x112>(x);   // row_shr:2
    x = dpp_max_f<0x114>(x);   // row_shr:4
    x = dpp_max_f<0x118>(x);   // row_shr:8
    x = dpp_max_f<0x142>(x);   // row_bcast:15
    x = dpp_max_f<0x143>(x);   // row_bcast:31
    return x;                  // full max valid in lane 63
}
__device__ __forceinline__ int wave_max_i(int x) {
    x = dpp_max_i<0x111>(x);
    x = dpp_max_i<0x112>(x);
    x = dpp_max_i<0x114>(x);
    x = dpp_max_i<0x118>(x);
    x = dpp_max_i<0x142>(x);
    x = dpp_max_i<0x143>(x);
    return x;                  // full max valid in lane 63
}

// pinit/istride: coord init source. cb0/cstride: centroid re-read source.
__global__ __launch_bounds__(T)
__attribute__((amdgpu_waves_per_eu(4, 4)))
void fps_kernel(float* __restrict__ out,
                const float* __restrict__ pinit, int istride,
                const float* __restrict__ cb0,  int cstride) {
#pragma clang fp contract(off)
    const int b    = blockIdx.x;
    const int t    = threadIdx.x;
    const int lane = t & 63;

    __shared__ unsigned long long s_pk4[4];

    const float* pb = pinit + (size_t)b * NN * istride;
    const float* cb = cb0  + (size_t)b * NN * cstride;

    float px[SLOTS], py[SLOTS], pz[SLOTS], dist[SLOTS];
#pragma unroll
    for (int j = 0; j < SLOTS; ++j) {
        const size_t r = (size_t)(j * T + t) * istride;
        px[j] = pb[r + 0];
        py[j] = pb[r + 1];
        pz[j] = pb[r + 2];
        dist[j] = 1e10f;
    }
    if (t < 4) s_pk4[t] = 0ull;

    float cx = cb[0], cy = cb[1], cz = cb[2];   // point 0
    int   far = 0;
    __syncthreads();

    int* idx_out = reinterpret_cast<int*>(out);

    for (int it = 0; it < NC; ++it) {
        if (t == 0) idx_out[((size_t)b * NC + it) * CC] = far;
        if (it == NC - 1) break;

        // ---- dist update (chain B1, bitwise-exact); 4 independent maxes ----
        float a0 = -1.0f, a1 = -1.0f, a2 = -1.0f, a3 = -1.0f;
#pragma unroll
        for (int j = 0; j < SLOTS; j += 4) {
            {
                const float dx = px[j] - cx, dy = py[j] - cy, dz = pz[j] - cz;
                const float d  = fmaf(dz, dz, fmaf(dx, dx, dy * dy));
                const float nd = fminf(dist[j], d);
                dist[j] = nd; a0 = fmaxf(a0, nd);
            }
            {
                const float dx = px[j+1] - cx, dy = py[j+1] - cy, dz = pz[j+1] - cz;
                const float d  = fmaf(dz, dz, fmaf(dx, dx, dy * dy));
                const float nd = fminf(dist[j+1], d);
                dist[j+1] = nd; a1 = fmaxf(a1, nd);
            }
            {
                const float dx = px[j+2] - cx, dy = py[j+2] - cy, dz = pz[j+2] - cz;
                const float d  = fmaf(dz, dz, fmaf(dx, dx, dy * dy));
                const float nd = fminf(dist[j+2], d);
                dist[j+2] = nd; a2 = fmaxf(a2, nd);
            }
            {
                const float dx = px[j+3] - cx, dy = py[j+3] - cy, dz = pz[j+3] - cz;
                const float d  = fmaf(dz, dz, fmaf(dx, dx, dy * dy));
                const float nd = fminf(dist[j+3], d);
                dist[j+3] = nd; a3 = fmaxf(a3, nd);
            }
        }
        const float lv = fmaxf(fmaxf(a0, a1), fmaxf(a2, a3));

        // ---- per-wave fused (value, index) reduce ----
        const float wv  = wave_max_f(lv);                         // lane63 full
        const int   wvb = __builtin_amdgcn_readlane(__float_as_int(wv), 63);
        int myc = 0;                                              // 0 = neutral
        if (__float_as_int(lv) == wvb) {                          // wave achievers
            const float gv = __int_as_float(wvb);
            int myi = 0x7fffffff;
#pragma unroll
            for (int j = SLOTS - 1; j >= 0; --j)                  // first slot kept
                myi = (dist[j] == gv) ? (j * T + t) : myi;
            myc = 0x7fffffff - myi;                               // complement
        }
        const int wc = wave_max_i(myc);                           // lane63 full

        if (lane == 63)
            atomicMax(&s_pk4[it & 3],
                      ((unsigned long long)(unsigned)wvb << 32) | (unsigned)wc);
        if (t == 0) s_pk4[(it + 2) & 3] = 0ull;                   // rotate reset
        __syncthreads();                                          // ONE barrier

        const unsigned long long pk = s_pk4[it & 3];
        far = 0x7fffffff - (int)(unsigned)(pk & 0xffffffffu);

        // ---- centroid reload (compact L2-resident buffer, or strided) ----
        cx = cb[(size_t)far * cstride + 0];
        cy = cb[(size_t)far * cstride + 1];
        cz = cb[(size_t)far * cstride + 2];
    }
}

// ---------------------------------------------------------------------------
// One-time xyz compaction: in[b][i][0..2] -> cpts[b][i*3+{0,1,2}] (12B rows).
// ---------------------------------------------------------------------------
__global__ __launch_bounds__(256) void compact_kernel(const float* __restrict__ in,
                                                      float* __restrict__ cpts) {
    const int gid = blockIdx.x * blockDim.x + threadIdx.x;   // one point each
    const int b   = gid >> 14;                               // NN == 16384
    const int i   = gid & (NN - 1);
    const float* src = in + ((size_t)b * NN + i) * CC;
    float* dst = cpts + ((size_t)b * NN + i) * 3;
    dst[0] = src[0];
    dst[1] = src[1];
    dst[2] = src[2];
}

// ---------------------------------------------------------------------------
// Gather kernel: one wave64 per output row (64 channels).
// ---------------------------------------------------------------------------
__global__ __launch_bounds__(256) void gather_kernel(const float* __restrict__ in,
                                                     float* out) {
    const int gid  = blockIdx.x * blockDim.x + threadIdx.x;
    const int row  = gid >> 6;     // 0 .. B*NC-1
    const int lane = gid & 63;     // channel
    const int b = row >> 12;       // NC == 4096
    const int idx = reinterpret_cast<const int*>(out)[(size_t)row * CC];
    const float v = in[((size_t)b * NN + idx) * CC + lane];
    out[(size_t)row * CC + lane] = v;
}

extern "C" void kernel_launch(void* const* d_in, const int* in_sizes, int n_in,
                              void* d_out, int out_size, void* d_ws, size_t ws_size,
                              hipStream_t stream) {
    const float* in = (const float*)d_in[0];
    float* out = (float*)d_out;

    const size_t ws_need = (size_t)BB * NN * 3 * sizeof(float);   // 6 MB
    if (ws_size >= ws_need) {
        float* cpts = (float*)d_ws;
        compact_kernel<<<(BB * NN) / 256, 256, 0, stream>>>(in, cpts);
        fps_kernel<<<BB, T, 0, stream>>>(out, cpts, 3, cpts, 3);
    } else {
        fps_kernel<<<BB, T, 0, stream>>>(out, in, CC, in, CC);
    }

    const int total = BB * NC * CC;          // 8,388,608
    gather_kernel<<<total / 256, 256, 0, stream>>>(in, out);
}